// Round 2
// baseline (867.866 us; speedup 1.0000x reference)
//
#include <hip/hip_runtime.h>
#include <cstdint>
#include <cstddef>

// HetroGNN fused: h = tanh(W_w @ concat(rel,ent) + b_w); s = u.h + b_u;
// att = softmax_n(mask ? -inf : s); out = tanh(sum_n att * ent).
//
// Round-2 structure: one WAVE owns one batch end-to-end. W_w staged once per
// block as RTN bf16 in LDS (XOR-swizzled, conflict-free b128 reads); A loaded
// global->VGPR in MFMA fragment order with hi/lo split (2 MFMA passes).
// No __syncthreads in the batch loop — waves are fully independent.

#define BLOCK 512
#define WPB 8           // waves per block
#define GRID 512        // 512 blocks x 8 waves = 4096 waves, 4 batches each

typedef __attribute__((ext_vector_type(8))) short short8;
typedef __attribute__((ext_vector_type(4))) float f32x4;

__device__ __forceinline__ float fast_tanh(float x) {
  float e = __expf(2.0f * x);   // saturates correctly at +/-inf
  return 1.0f - 2.0f / (e + 1.0f);
}

// pack 2 fp32 -> truncated-bf16 pair (hi) + residual-bf16 pair (lo)
__device__ __forceinline__ void cvt2_hilo(float a0, float a1,
                                          unsigned int& hi, unsigned int& lo) {
  unsigned int u0 = __float_as_uint(a0), u1 = __float_as_uint(a1);
  hi = (u0 >> 16) | (u1 & 0xFFFF0000u);
  float r0 = a0 - __uint_as_float(u0 & 0xFFFF0000u);
  float r1 = a1 - __uint_as_float(u1 & 0xFFFF0000u);
  lo = (__float_as_uint(r0) >> 16) | (__float_as_uint(r1) & 0xFFFF0000u);
}

__device__ __forceinline__ unsigned int bf16_rtn(float f) {
  unsigned int u = __float_as_uint(f);
  u += 0x7FFFu + ((u >> 16) & 1u);
  return u >> 16;
}

__global__ __launch_bounds__(BLOCK, 4) void hetrognn_kernel(
    const float* __restrict__ rel, const float* __restrict__ ent,
    const int* __restrict__ mask, const float* __restrict__ Ww,
    const float* __restrict__ bw, const float* __restrict__ Wu,
    const float* __restrict__ bu, float* __restrict__ out, int Btot) {
  // W as bf16 RTN: [d][k] row-major, row stride 256 shorts, k-chunk XOR-swizzle
  // by row parity ((d&1)<<5 shorts = 16 dwords) -> uniform banks on frag reads.
  __shared__ unsigned short Wlds[128 * 256];  // 64 KB

  const int tid = threadIdx.x;
  const int lane = tid & 63;
  const int wv = tid >> 6;
  const int l15 = lane & 15;
  const int quad = lane >> 4;

  // ---- one-time: stage W into LDS (RTN bf16) ----
#pragma unroll
  for (int it = 0; it < 16; ++it) {
    const int i = tid + it * BLOCK;      // float4 index 0..8191
    const int d = i >> 6;                // 64 float4 per 256-wide row
    const int k4 = (i & 63) << 2;
    float4 w = *(const float4*)(Ww + d * 256 + k4);
    unsigned int p0 = (bf16_rtn(w.x) & 0xFFFFu) | (bf16_rtn(w.y) << 16);
    unsigned int p1 = (bf16_rtn(w.z) & 0xFFFFu) | (bf16_rtn(w.w) << 16);
    const int kx = k4 ^ ((d & 1) << 5);  // swizzle
    *(uint2*)&Wlds[d * 256 + kx] = make_uint2(p0, p1);
  }
  // per-lane u[d], bw[d] for d = dt*16 + l15
  float uv[8], bwv[8];
#pragma unroll
  for (int dt = 0; dt < 8; ++dt) {
    uv[dt] = Wu[dt * 16 + l15];
    bwv[dt] = bw[dt * 16 + l15];
  }
  const float buv = bu[0];
  __syncthreads();  // the ONLY block barrier

  const int gw = blockIdx.x * WPB + wv;
  const int nw = gridDim.x * WPB;
  const int swz = (l15 & 1) << 5;  // W read swizzle for this lane's d rows

  for (int b = gw; b < Btot; b += nw) {
    const float* rel_b = rel + (size_t)b * 3840;
    const float* ent_b = ent + (size_t)b * 3840;

    // acc[mt][dt]: rows n = mt*16 + quad*4 + reg, col d = dt*16 + l15.
    // Fold b_w into the accumulator init.
    f32x4 acc[2][8];
#pragma unroll
    for (int dt = 0; dt < 8; ++dt) {
      f32x4 ini = {bwv[dt], bwv[dt], bwv[dt], bwv[dt]};
      acc[0][dt] = ini;
      acc[1][dt] = ini;
    }

    const int r0 = l15;       // mt0 row
    const int r1 = 16 + l15;  // mt1 row (invalid when >= 30)
    const bool v1 = (r1 < 30);

#pragma unroll
    for (int ks = 0; ks < 8; ++ks) {
      const int f = ks * 32 + quad * 8;  // concat feature base for this lane
      const float* base = (ks < 4) ? rel_b : (ent_b - 128);
      float4 a0 = *(const float4*)(base + r0 * 128 + f);
      float4 a1 = *(const float4*)(base + r0 * 128 + f + 4);
      float4 c0 = make_float4(0.f, 0.f, 0.f, 0.f), c1 = c0;
      if (v1) {
        c0 = *(const float4*)(base + r1 * 128 + f);
        c1 = *(const float4*)(base + r1 * 128 + f + 4);
      }
      // pack A fragments (hi = trunc, lo = residual; exact to ~2^-16)
      union { short8 s; unsigned int u[4]; } ah0, al0, ah1, al1;
      cvt2_hilo(a0.x, a0.y, ah0.u[0], al0.u[0]);
      cvt2_hilo(a0.z, a0.w, ah0.u[1], al0.u[1]);
      cvt2_hilo(a1.x, a1.y, ah0.u[2], al0.u[2]);
      cvt2_hilo(a1.z, a1.w, ah0.u[3], al0.u[3]);
      cvt2_hilo(c0.x, c0.y, ah1.u[0], al1.u[0]);
      cvt2_hilo(c0.z, c0.w, ah1.u[1], al1.u[1]);
      cvt2_hilo(c1.x, c1.y, ah1.u[2], al1.u[2]);
      cvt2_hilo(c1.z, c1.w, ah1.u[3], al1.u[3]);

      const int kbase = (ks * 32 + quad * 8);
#pragma unroll
      for (int dt = 0; dt < 8; ++dt) {
        const unsigned short* wp =
            &Wlds[(dt * 16 + l15) * 256 + (kbase ^ swz)];
        short8 wf = *(const short8*)wp;
        acc[0][dt] = __builtin_amdgcn_mfma_f32_16x16x32_bf16(ah0.s, wf, acc[0][dt], 0, 0, 0);
        acc[0][dt] = __builtin_amdgcn_mfma_f32_16x16x32_bf16(al0.s, wf, acc[0][dt], 0, 0, 0);
        acc[1][dt] = __builtin_amdgcn_mfma_f32_16x16x32_bf16(ah1.s, wf, acc[1][dt], 0, 0, 0);
        acc[1][dt] = __builtin_amdgcn_mfma_f32_16x16x32_bf16(al1.s, wf, acc[1][dt], 0, 0, 0);
      }
    }

    // ---- epilogue: score partials s[n] = sum_d u[d] * tanh(hpre[n][d]) ----
    float sp0[4] = {0.f, 0.f, 0.f, 0.f}, sp1[4] = {0.f, 0.f, 0.f, 0.f};
#pragma unroll
    for (int dt = 0; dt < 8; ++dt) {
#pragma unroll
      for (int reg = 0; reg < 4; ++reg) {
        sp0[reg] += uv[dt] * fast_tanh(acc[0][dt][reg]);
        sp1[reg] += uv[dt] * fast_tanh(acc[1][dt][reg]);
      }
    }
    // reduce over the 16 l15 lanes (d dimension); quad is the row group
#pragma unroll
    for (int m = 1; m < 16; m <<= 1) {
#pragma unroll
      for (int reg = 0; reg < 4; ++reg) {
        sp0[reg] += __shfl_xor(sp0[reg], m, 64);
        sp1[reg] += __shfl_xor(sp1[reg], m, 64);
      }
    }
    const int rsel = l15 & 3;
    float s0 = (rsel == 0) ? sp0[0] : (rsel == 1) ? sp0[1] : (rsel == 2) ? sp0[2] : sp0[3];
    float s1 = (rsel == 0) ? sp1[0] : (rsel == 1) ? sp1[1] : (rsel == 2) ? sp1[2] : sp1[3];
    const int n0 = quad * 4 + rsel;  // 0..15
    const int n1 = n0 + 16;          // 16..31

    // ---- in-wave softmax over n ----
    const int m0 = mask[(size_t)b * 30 + n0];
    const int m1 = (n1 < 30) ? mask[(size_t)b * 30 + n1] : 1;
    float v0 = m0 ? -INFINITY : (s0 + buv);
    float w1 = m1 ? -INFINITY : (s1 + buv);
    float mx = fmaxf(v0, w1);
#pragma unroll
    for (int m = 1; m < 64; m <<= 1) mx = fmaxf(mx, __shfl_xor(mx, m, 64));
    float e0 = m0 ? 0.f : __expf(v0 - mx);
    float e1 = m1 ? 0.f : __expf(w1 - mx);
    float t = ((l15 & 12) == 0) ? (e0 + e1) : 0.f;  // drop 4x replicas
#pragma unroll
    for (int m = 1; m < 64; m <<= 1) t += __shfl_xor(t, m, 64);
    const float inv = 1.0f / t;
    const float att0 = e0 * inv, att1 = e1 * inv;

    // ---- output: out[b,d] = tanh(sum_n att[n] * ent[b,n,d]) ----
    const int d0 = lane << 1;  // each lane: 2 consecutive d
    float o0 = 0.f, o1 = 0.f;
#pragma unroll
    for (int n = 0; n < 30; ++n) {
      const int sl = ((n & 15) >> 2) * 16 + (n & 3);
      const float a = (n < 16) ? __shfl(att0, sl, 64) : __shfl(att1, sl, 64);
      float2 ev = *(const float2*)(ent_b + n * 128 + d0);
      o0 += a * ev.x;
      o1 += a * ev.y;
    }
    float2 ov = make_float2(fast_tanh(o0), fast_tanh(o1));
    *(float2*)(out + (size_t)b * 128 + d0) = ov;
  }
}

extern "C" void kernel_launch(void* const* d_in, const int* in_sizes, int n_in,
                              void* d_out, int out_size, void* d_ws, size_t ws_size,
                              hipStream_t stream) {
  const float* rel = (const float*)d_in[0];
  const float* ent = (const float*)d_in[1];
  const int* mask = (const int*)d_in[2];
  const float* Ww = (const float*)d_in[3];
  const float* bw = (const float*)d_in[4];
  const float* Wu = (const float*)d_in[5];
  const float* bu = (const float*)d_in[6];
  float* out = (float*)d_out;
  const int Btot = in_sizes[0] / 3840;  // B*N*D / (30*128)
  hipLaunchKernelGGL(hetrognn_kernel, dim3(GRID), dim3(BLOCK), 0, stream,
                     rel, ent, mask, Ww, bw, Wu, bu, out, Btot);
}